// Round 9
// baseline (382.815 us; speedup 1.0000x reference)
//
#include <hip/hip_runtime.h>
#include <cstdint>
#include <cstddef>

// Problem constants: B=4, S=2048, D=1024
#define BB 4
#define SS 2048
#define DD 1024

typedef _Float16 f16;
typedef _Float16 f16x8 __attribute__((ext_vector_type(8)));
typedef _Float16 f16x4 __attribute__((ext_vector_type(4)));
typedef float fx4 __attribute__((ext_vector_type(4)));

// ---------------------------------------------------------------------------
// async global->LDS, 16B per lane. LDS dest must be wave-uniform base + lane*16.
// ---------------------------------------------------------------------------
__device__ __forceinline__ void async_copy16(void* lds, const void* g) {
  __builtin_amdgcn_global_load_lds(
      (__attribute__((address_space(1))) void*)const_cast<void*>(g),
      (__attribute__((address_space(3))) void*)lds,
      16, 0, 0);
}

enum { EPI_BIAS = 0, EPI_MASKEXP = 1, EPI_ROWSCALE = 2, EPI_QKV = 3, EPI_BIAS_ATOMIC = 4 };

// ---------------------------------------------------------------------------
// NT GEMM: C[M,N] = epilogue(scale * (A[M,K] @ Bt[N,K]^T))
// 128x128 tile, BK=32, 256 threads (4 waves 2x2), mfma_f32_16x16x32_f16.
// R7 structure (proven 336.7us): LDS double-buffer, one barrier/iter.
// R8 (TM=64 for small-grid GEMMs) regressed — staging:MFMA ratio loss beat
// the occupancy gain; reverted. R9 adds EPI_BIAS_ATOMIC for split-K GEMM4:
// grid.z = K-split index via strideA/strideB = k-offset (512), strideC = 0;
// partial sums atomicAdd into fp32 out (zeroed in k_prep); bias from split 0
// only. Split-K keeps the per-iter staging:MFMA ratio intact (unlike R8).
//
// R7 HAZARD RULE (from R6's nondeterministic failure): regular VGPR global
// loads must NEVER be in flight together with global_load_lds LDS-DMA (both
// share vmcnt; mixed retirement under-waits). MASKEXP mask pack runs FIRST,
// then __syncthreads(), then the first LDS-DMA.
//
// LDS K-chunks XOR-swizzled (R2: 6.29e6 conflict cycles -> 0). Staging
// thread t writes LDS chunk t; fetches global k-chunk (t&3)^((t>>3)&3).
// Read side: frag(row,quad) at chunk row*4 + (quad ^ ((r16>>1)&3)).
//
// EPI_QKV (GEMM1): tileN<2048 -> packed QK[8192x2048]; else V^T straight to
//   Vt[b][d][s].
// EPI_MASKEXP: C = mask ? 0 : exp(scale*acc); atomic row sums; 2KB LDS
//   bitmask packed pre-loop. (No max-subtraction: scores ~N(0,1); f16
//   overflow needs >11 sigma; masked -> exact 0.)
// EPI_ROWSCALE: C = acc * scale / rowSum[row]
// ---------------------------------------------------------------------------
template <typename OutT, int MODE>
__global__ __launch_bounds__(256, 2) void gemm_nt(
    const f16* __restrict__ A, long long strideA, int lda,
    const f16* __restrict__ Bt, long long strideB, int ldb,
    OutT* __restrict__ C, long long strideC, int ldc,
    const float* __restrict__ bias, const int* __restrict__ mask,
    float* __restrict__ rowSum, f16* __restrict__ vt, float scale, int K) {
  // 32KB dbuf (2 x (As 8K + Bs 8K)); +2KB mask bitmask for MASKEXP only
  constexpr int SMEM_BYTES = (MODE == EPI_MASKEXP) ? 34816 : 32768;
  __shared__ __align__(16) char smem[SMEM_BYTES];
  uint32_t* lmb = (uint32_t*)(smem + 32768);  // 512 words = 128x128 bits

  const int t = threadIdx.x;
  const int lane = t & 63;
  const int wid = t >> 6;
  const long long bz = blockIdx.z;
  const int tileM = blockIdx.y * 128;
  const int tileN = blockIdx.x * 128;

  const f16* Ab = A + bz * strideA;
  const f16* Bb = Bt + bz * strideB;
  OutT* Cb = C + bz * strideC;

  // Staging map (swizzled): row = t/4, global k-chunk = (t&3)^((t>>3)&3).
  const int sr = t >> 2;
  const int sc = (((t & 3) ^ ((t >> 3) & 3)) * 8);
  const f16* pa0 = Ab + (size_t)(tileM + sr) * lda + sc;
  const f16* pa1 = Ab + (size_t)(tileM + 64 + sr) * lda + sc;
  const f16* pb0 = Bb + (size_t)(tileN + sr) * ldb + sc;
  const f16* pb1 = Bb + (size_t)(tileN + 64 + sr) * ldb + sc;
  const int tb = t * 16;  // byte offset of this thread's 16B chunk

  const int waveM = (wid >> 1) * 64;
  const int waveN = (wid & 1) * 64;
  const int r16 = lane & 15;
  const int quad = lane >> 4;
  const int sw = (r16 >> 1) & 3;  // read-side swizzle term

  if constexpr (MODE == EPI_MASKEXP) {
    // Pack 128x128 int32 mask tile -> 512-word LDS bitmask. BEFORE any DMA.
    const int* maskb = mask + bz * (long long)SS * SS;
#pragma unroll
    for (int it = 0; it < 16; ++it) {
      const int f = it * 256 + t;
      const int4 mv =
          *(const int4*)&maskb[(size_t)(tileM + (f >> 5)) * SS + tileN + (f & 31) * 4];
      uint32_t val = (mv.x ? 1u : 0u) | (mv.y ? 2u : 0u) | (mv.z ? 4u : 0u) |
                     (mv.w ? 8u : 0u);
      val <<= (t & 7) * 4;
      val |= __shfl_xor(val, 1, 64);
      val |= __shfl_xor(val, 2, 64);
      val |= __shfl_xor(val, 4, 64);
      if ((t & 7) == 0) lmb[it * 32 + (t >> 3)] = val;
    }
    __syncthreads();  // drain pack vmcnt + publish lmb BEFORE first LDS-DMA
  }

  const int nIter = K >> 5;
  // prologue: prefetch tile 0 into buffer 0
  {
    char* b0 = smem;
    async_copy16(b0 + tb, pa0);
    async_copy16(b0 + 4096 + tb, pa1);
    async_copy16(b0 + 8192 + tb, pb0);
    async_copy16(b0 + 12288 + tb, pb1);
  }

  fx4 acc[4][4] = {};

#pragma unroll 2
  for (int i = 0; i < nIter; ++i) {
    __syncthreads();  // drains vmcnt (prefetch i) + lgkm (reads of i-1)
    if (i + 1 < nIter) {
      char* nb = smem + ((i + 1) & 1) * 16384;
      const int k = (i + 1) << 5;
      async_copy16(nb + tb, pa0 + k);
      async_copy16(nb + 4096 + tb, pa1 + k);
      async_copy16(nb + 8192 + tb, pb0 + k);
      async_copy16(nb + 12288 + tb, pb1 + k);
    }
    const f16* As = (const f16*)(smem + (i & 1) * 16384);
    const f16* Bs = As + 4096;

    f16x8 af[4], bf[4];
#pragma unroll
    for (int x = 0; x < 4; ++x)
      af[x] = *(const f16x8*)&As[(waveM + x * 16 + r16) * 32 + (quad ^ sw) * 8];
#pragma unroll
    for (int x = 0; x < 4; ++x)
      bf[x] = *(const f16x8*)&Bs[(waveN + x * 16 + r16) * 32 + (quad ^ sw) * 8];

#pragma unroll
    for (int x = 0; x < 4; ++x)
#pragma unroll
      for (int j = 0; j < 4; ++j)
        acc[x][j] =
            __builtin_amdgcn_mfma_f32_16x16x32_f16(af[x], bf[j], acc[x][j], 0, 0, 0);
  }

  // C/D layout (verified, dtype-independent): col = lane&15, row = quad*4 + reg.
  if constexpr (MODE == EPI_BIAS) {
#pragma unroll
    for (int j = 0; j < 4; ++j) {
      const int col = tileN + waveN + j * 16 + r16;
      const float bv = bias[col];
#pragma unroll
      for (int i = 0; i < 4; ++i) {
#pragma unroll
        for (int r = 0; r < 4; ++r) {
          const int row = tileM + waveM + i * 16 + quad * 4 + r;
          Cb[(size_t)row * ldc + col] = (OutT)(acc[i][j][r] * scale + bv);
        }
      }
    }
  } else if constexpr (MODE == EPI_BIAS_ATOMIC) {
    // split-K partial: atomically accumulate into fp32 C (zeroed in k_prep);
    // bias contributed by split 0 only.
#pragma unroll
    for (int j = 0; j < 4; ++j) {
      const int col = tileN + waveN + j * 16 + r16;
      const float bv = (bz == 0) ? bias[col] : 0.0f;
#pragma unroll
      for (int i = 0; i < 4; ++i) {
#pragma unroll
        for (int r = 0; r < 4; ++r) {
          const int row = tileM + waveM + i * 16 + quad * 4 + r;
          atomicAdd((float*)&Cb[(size_t)row * ldc + col], acc[i][j][r] * scale + bv);
        }
      }
    }
  } else if constexpr (MODE == EPI_QKV) {
    if (tileN < 2 * DD) {
      // packed QK output [8192 x 2048]
#pragma unroll
      for (int j = 0; j < 4; ++j) {
        const int col = tileN + waveN + j * 16 + r16;
        const float bv = bias[col];
#pragma unroll
        for (int i = 0; i < 4; ++i) {
#pragma unroll
          for (int r = 0; r < 4; ++r) {
            const int row = tileM + waveM + i * 16 + quad * 4 + r;
            Cb[(size_t)row * ldc + col] = (OutT)(acc[i][j][r] + bv);
          }
        }
      }
    } else {
      // V columns -> write transposed into Vt[b][d][s]
      const int b = tileM >> 11;  // 128-row tiles never straddle batch
      const int s0 = (tileM & 2047) + waveM;
      f16* vb = vt + (size_t)b * DD * SS;
#pragma unroll
      for (int j = 0; j < 4; ++j) {
        const int col = tileN + waveN + j * 16 + r16;
        const float bv = bias[col];
        const int d = col - 2 * DD;
#pragma unroll
        for (int i = 0; i < 4; ++i) {
          const int s = s0 + i * 16 + quad * 4;
          f16x4 v4;
#pragma unroll
          for (int r = 0; r < 4; ++r) v4[r] = (f16)(acc[i][j][r] + bv);
          *(f16x4*)&vb[(size_t)d * SS + s] = v4;
        }
      }
    }
  } else if constexpr (MODE == EPI_MASKEXP) {
    // Bitmask read: word(lr,lc) = lr*4 + (lc>>5), bit lc&31. Broadcast
    // across r16, 4 words across quads — conflict-free.
#pragma unroll
    for (int i = 0; i < 4; ++i) {
#pragma unroll
      for (int r = 0; r < 4; ++r) {
        const int lr = waveM + i * 16 + quad * 4 + r;
        const int row = tileM + lr;
        const uint32_t w0 = lmb[lr * 4 + (waveN >> 5)];
        const uint32_t w1 = lmb[lr * 4 + (waveN >> 5) + 1];
        float part = 0.0f;
#pragma unroll
        for (int j = 0; j < 4; ++j) {
          const int lc = waveN + j * 16 + r16;
          const int bitpos = j * 16 + r16;  // within w0:w1
          const uint32_t mv = ((j < 2 ? w0 : w1) >> (bitpos & 31)) & 1u;
          const float e = mv ? 0.0f : __expf(acc[i][j][r] * scale);
          Cb[(size_t)row * ldc + tileN + lc] = (OutT)e;
          part += e;
        }
#pragma unroll
        for (int d = 1; d < 16; d <<= 1) part += __shfl_xor(part, d, 64);
        if (r16 == 0) atomicAdd(&rowSum[bz * SS + row], part);
      }
    }
  } else {  // EPI_ROWSCALE
#pragma unroll
    for (int i = 0; i < 4; ++i) {
#pragma unroll
      for (int r = 0; r < 4; ++r) {
        const int row = tileM + waveM + i * 16 + quad * 4 + r;
        const float inv = scale / rowSum[bz * SS + row];
#pragma unroll
        for (int j = 0; j < 4; ++j) {
          const int col = tileN + waveN + j * 16 + r16;
          Cb[(size_t)row * ldc + col] = (OutT)(acc[i][j][r] * inv);
        }
      }
    }
  }
}

// ---------------------------------------------------------------------------
// Merged prep: X->f16 conv | W_qkv^T | W_out^T | rowSum zero | out zero.
// Block-uniform path select. grid = 8192 + 3072 + 1024 + 32 + 8192 = 20512.
// ---------------------------------------------------------------------------
__global__ __launch_bounds__(256) void k_prep(
    const float* __restrict__ X, f16* __restrict__ Xh,
    const float* __restrict__ Wqkv, f16* __restrict__ Wqkvt,
    const float* __restrict__ Wout, f16* __restrict__ Woutt,
    float* __restrict__ rowSum, float* __restrict__ outZ) {
  int bid = blockIdx.x;
  const int t = threadIdx.x;
  if (bid < 8192) {  // X conv: 2097152 float4s
    const int i = bid * 256 + t;
    const float4 v = ((const float4*)X)[i];
    f16x4 h = {(f16)v.x, (f16)v.y, (f16)v.z, (f16)v.w};
    ((f16x4*)Xh)[i] = h;
    return;
  }
  bid -= 8192;
  if (bid < 8192) {  // out zero (split-K GEMM4 accumulates atomically)
    const float4 z = {0.0f, 0.0f, 0.0f, 0.0f};
    ((float4*)outZ)[bid * 256 + t] = z;
    return;
  }
  bid -= 8192;
  __shared__ float tile[32][33];
  const int tx = t & 31, ty = t >> 5;
  if (bid < 3072) {  // Wqkv [1024][3072] -> Wqkvt [3072][1024]
    const int bx = (bid % 96) * 32, by = (bid / 96) * 32;
    for (int i2 = ty; i2 < 32; i2 += 8)
      tile[i2][tx] = Wqkv[(size_t)(by + i2) * 3072 + bx + tx];
    __syncthreads();
    for (int i2 = ty; i2 < 32; i2 += 8)
      Wqkvt[(size_t)(bx + i2) * 1024 + by + tx] = (f16)tile[tx][i2];
    return;
  }
  bid -= 3072;
  if (bid < 1024) {  // Wout [1024][1024] -> Woutt [1024][1024]
    const int bx = (bid & 31) * 32, by = (bid >> 5) * 32;
    for (int i2 = ty; i2 < 32; i2 += 8)
      tile[i2][tx] = Wout[(size_t)(by + i2) * 1024 + bx + tx];
    __syncthreads();
    for (int i2 = ty; i2 < 32; i2 += 8)
      Woutt[(size_t)(bx + i2) * 1024 + by + tx] = (f16)tile[tx][i2];
    return;
  }
  bid -= 1024;  // rowSum zero: 32 blocks x 256 = 8192
  rowSum[bid * 256 + t] = 0.0f;
}

// ---------------------------------------------------------------------------
// kernel_launch
// inputs: X[4,2048,1024]f32, mask[4,2048,2048]i32, W_qkv[1024,3072]f32,
//         b_qkv[3072]f32, W_out[1024,1024]f32, b_out[1024]f32
// out:    [4,2048,1024] f32
// ---------------------------------------------------------------------------
extern "C" void kernel_launch(void* const* d_in, const int* in_sizes, int n_in,
                              void* d_out, int out_size, void* d_ws, size_t ws_size,
                              hipStream_t stream) {
  const float* X = (const float*)d_in[0];
  const int* mask = (const int*)d_in[1];
  const float* Wqkv = (const float*)d_in[2];
  const float* bqkv = (const float*)d_in[3];
  const float* Wout = (const float*)d_in[4];
  const float* bout = (const float*)d_in[5];
  float* out = (float*)d_out;

  char* ws = (char*)d_ws;
  // ws layout (bytes); total ~125.9 MB
  f16* Xh = (f16*)(ws + 0);                    // 8192*1024   (16.78 MB)
  f16* Wqkvt = (f16*)(ws + 16777216);          // 3072*1024   ( 6.29 MB)
  f16* Woutt = (f16*)(ws + 23068672);          // 1024*1024   ( 2.10 MB)
  f16* QK = (f16*)(ws + 25165824);             // 8192*2048   (33.55 MB) packed Q|K
  f16* Vt = (f16*)(ws + 58720256);             // 4*1024*2048 (16.78 MB)
  f16* E = (f16*)(ws + 75497472);              // 4*2048*2048 (33.55 MB) exp(scores)
  f16* Ctx = (f16*)(ws + 109051904);           // 8192*1024   (16.78 MB)
  float* rowSum = (float*)(ws + 125829120);    // 8192 f32    (32 KB)

  // 1) merged prep: conv + W transposes + rowSum zero + out zero
  k_prep<<<dim3(20512), dim3(256), 0, stream>>>(X, Xh, Wqkv, Wqkvt, Wout, Woutt,
                                                rowSum, out);

  // 2) QKV proj [8192 x 3072], K=1024: Q,K -> packed QK; V -> Vt (transposed)
  gemm_nt<f16, EPI_QKV><<<dim3(24, 64, 1), dim3(256), 0, stream>>>(
      Xh, 0LL, DD, Wqkvt, 0LL, DD, QK, 0LL, 2 * DD, bqkv, nullptr, nullptr, Vt,
      1.0f, DD);

  // 3) E = where(mask, 0, exp(Q @ K^T / 32)); rowSum += row sums  [2048 x 2048] x4
  gemm_nt<f16, EPI_MASKEXP><<<dim3(16, 16, 4), dim3(256), 0, stream>>>(
      QK, (long long)SS * 2 * DD, 2 * DD, QK + DD, (long long)SS * 2 * DD, 2 * DD,
      E, (long long)SS * SS, SS, nullptr, mask, rowSum, nullptr, 0.03125f, DD);

  // 4) ctx = (E @ V) / rowSum   [2048 x 1024] x4, K=2048  (R7 config, TM=128)
  gemm_nt<f16, EPI_ROWSCALE><<<dim3(8, 16, 4), dim3(256), 0, stream>>>(
      E, (long long)SS * SS, SS, Vt, (long long)DD * SS, SS, Ctx,
      (long long)SS * DD, DD, nullptr, nullptr, rowSum, nullptr, 1.0f, SS);

  // 5) out += ctx @ W_out + b   [8192 x 1024], split-K=2 (z = split index,
  //    k-offset 512 via strideA/strideB; strideC=0; fp32 atomic epilogue)
  gemm_nt<float, EPI_BIAS_ATOMIC><<<dim3(8, 64, 2), dim3(256), 0, stream>>>(
      Ctx, 512LL, DD, Woutt, 512LL, DD, out, 0LL, DD, bout, nullptr, nullptr,
      nullptr, 1.0f, 512);
}

// Round 10
// 343.135 us; speedup vs baseline: 1.1156x; 1.1156x over previous
//
#include <hip/hip_runtime.h>
#include <cstdint>
#include <cstddef>

// Problem constants: B=4, S=2048, D=1024
#define BB 4
#define SS 2048
#define DD 1024

typedef _Float16 f16;
typedef _Float16 f16x8 __attribute__((ext_vector_type(8)));
typedef _Float16 f16x4 __attribute__((ext_vector_type(4)));
typedef float fx4 __attribute__((ext_vector_type(4)));

// ---------------------------------------------------------------------------
// async global->LDS, 16B per lane. LDS dest must be wave-uniform base + lane*16.
// ---------------------------------------------------------------------------
__device__ __forceinline__ void async_copy16(void* lds, const void* g) {
  __builtin_amdgcn_global_load_lds(
      (__attribute__((address_space(1))) void*)const_cast<void*>(g),
      (__attribute__((address_space(3))) void*)lds,
      16, 0, 0);
}

enum { EPI_BIAS = 0, EPI_MASKEXP = 1, EPI_ROWSCALE = 2, EPI_QKV = 3 };

// ---------------------------------------------------------------------------
// NT GEMM: C[M,N] = epilogue(scale * (A[M,K] @ Bt[N,K]^T))
// 128x128 tile, BK = 32 or 64, 256 threads (4 waves 2x2), mfma 16x16x32_f16.
// R7 structure (proven 336.7us): LDS double-buffer, one barrier/iter.
//
// R10: BK=64 for the grid-limited dispatches (GEMM3/GEMM4: 512 blocks =
// 2 blocks/CU regardless of LDS, so 64KB/block is occupancy-free). Halves
// the barrier count at constant bytes-staged-per-MFMA — attacks the barrier
// drain stall without the R8 (staging-ratio) or R9 (atomic-traffic)
// mistakes. GEMM1/GEMM2 keep BK=32 (their residency WOULD halve).
// Failed history: R5 no-LDS 1.8x regress; R8 TM=64 regress; R9 split-K
// atomics regress.
//
// R7 HAZARD RULE (from R6's nondeterministic failure): regular VGPR global
// loads must NEVER be in flight together with global_load_lds LDS-DMA (both
// share vmcnt; mixed retirement under-waits). MASKEXP mask pack runs FIRST,
// then __syncthreads(), then the first LDS-DMA. Epilogue global loads run
// after the last barrier with no DMA outstanding.
//
// LDS swizzles (conflict-free, verified R2 + algebra):
//  BK=32: stage thread t -> LDS chunk t, fetches global k-chunk
//         (t&3)^((t>>3)&3); read frag(row,quad) at chunk row*4 +
//         (quad ^ ((r16>>1)&3)).
//  BK=64: LDS chunk c (= row*8 + s_l) holds global k-chunk s_l ^ (row&7);
//         read frag(row,ks,quad) at chunk row*8 + ((ks*4+quad) ^ (r16&7))
//         -> 8 distinct bank groups x 2 lanes = free.
//
// EPI_QKV (GEMM1): tileN<2048 -> packed QK[8192x2048]; else V^T straight to
//   Vt[b][d][s].
// EPI_MASKEXP: C = mask ? 0 : exp(scale*acc); atomic row sums; 2KB LDS
//   bitmask packed pre-loop. (No max-subtraction: scores ~N(0,1); f16
//   overflow needs >11 sigma; masked -> exact 0.)
// EPI_ROWSCALE: C = acc * scale / rowSum[row]
// ---------------------------------------------------------------------------
template <typename OutT, int MODE, int BK>
__global__ __launch_bounds__(256, 2) void gemm_nt(
    const f16* __restrict__ A, long long strideA, int lda,
    const f16* __restrict__ Bt, long long strideB, int ldb,
    OutT* __restrict__ C, long long strideC, int ldc,
    const float* __restrict__ bias, const int* __restrict__ mask,
    float* __restrict__ rowSum, f16* __restrict__ vt, float scale, int K) {
  constexpr int ASZ = 128 * BK * 2;   // A bytes per buffer (= B bytes)
  constexpr int BUFSZ = 2 * ASZ;      // per-buffer total
  constexpr int SMEM_BYTES = 2 * BUFSZ + ((MODE == EPI_MASKEXP) ? 2048 : 0);
  __shared__ __align__(16) char smem[SMEM_BYTES];
  uint32_t* lmb = (uint32_t*)(smem + 2 * BUFSZ);  // 512 words (MASKEXP only)

  const int t = threadIdx.x;
  const int lane = t & 63;
  const int wid = t >> 6;
  const long long bz = blockIdx.z;
  const int tileM = blockIdx.y * 128;
  const int tileN = blockIdx.x * 128;

  const f16* Ab = A + bz * strideA;
  const f16* Bb = Bt + bz * strideB;
  OutT* Cb = C + bz * strideC;

  const int waveM = (wid >> 1) * 64;
  const int waveN = (wid & 1) * 64;
  const int r16 = lane & 15;
  const int quad = lane >> 4;
  const int sw = (r16 >> 1) & 3;  // BK=32 read-side swizzle term
  const int tb = t * 16;          // byte offset of this thread's 16B chunk

  // --- staging pointers ---
  // BK=32: 4 chunks/thread (legacy proven map)
  const f16* pa0;
  const f16* pa1;
  const f16* pb0;
  const f16* pb1;
  // BK=64: 8 chunks/thread
  const f16* pg[8];
  int loff[8];

  if constexpr (BK == 32) {
    const int sr = t >> 2;
    const int sc = (((t & 3) ^ ((t >> 3) & 3)) * 8);
    pa0 = Ab + (size_t)(tileM + sr) * lda + sc;
    pa1 = Ab + (size_t)(tileM + 64 + sr) * lda + sc;
    pb0 = Bb + (size_t)(tileN + sr) * ldb + sc;
    pb1 = Bb + (size_t)(tileN + 64 + sr) * ldb + sc;
  } else {
#pragma unroll
    for (int h = 0; h < 4; ++h) {  // A: chunks 0..1023
      const int c = h * 256 + t;
      const int row = c >> 3;
      const int sg = (c & 7) ^ (row & 7);
      pg[h] = Ab + (size_t)(tileM + row) * lda + sg * 8;
      loff[h] = c * 16;
    }
#pragma unroll
    for (int h = 4; h < 8; ++h) {  // B: chunks 0..1023 of B half
      const int c = (h - 4) * 256 + t;
      const int row = c >> 3;
      const int sg = (c & 7) ^ (row & 7);
      pg[h] = Bb + (size_t)(tileN + row) * ldb + sg * 8;
      loff[h] = ASZ + c * 16;
    }
  }

  if constexpr (MODE == EPI_MASKEXP) {
    // Pack 128x128 int32 mask tile -> 512-word LDS bitmask. BEFORE any DMA.
    const int* maskb = mask + bz * (long long)SS * SS;
#pragma unroll
    for (int it = 0; it < 16; ++it) {
      const int f = it * 256 + t;
      const int4 mv =
          *(const int4*)&maskb[(size_t)(tileM + (f >> 5)) * SS + tileN + (f & 31) * 4];
      uint32_t val = (mv.x ? 1u : 0u) | (mv.y ? 2u : 0u) | (mv.z ? 4u : 0u) |
                     (mv.w ? 8u : 0u);
      val <<= (t & 7) * 4;
      val |= __shfl_xor(val, 1, 64);
      val |= __shfl_xor(val, 2, 64);
      val |= __shfl_xor(val, 4, 64);
      if ((t & 7) == 0) lmb[it * 32 + (t >> 3)] = val;
    }
    __syncthreads();  // drain pack vmcnt + publish lmb BEFORE first LDS-DMA
  }

  auto stage = [&](char* buf, int k) {
    if constexpr (BK == 32) {
      async_copy16(buf + tb, pa0 + k);
      async_copy16(buf + 4096 + tb, pa1 + k);
      async_copy16(buf + 8192 + tb, pb0 + k);
      async_copy16(buf + 12288 + tb, pb1 + k);
    } else {
#pragma unroll
      for (int h = 0; h < 8; ++h) async_copy16(buf + loff[h], pg[h] + k);
    }
  };

  const int nIter = K / BK;
  stage(smem, 0);  // prologue: prefetch tile 0 into buffer 0

  fx4 acc[4][4] = {};

#pragma unroll 2
  for (int i = 0; i < nIter; ++i) {
    __syncthreads();  // drains vmcnt (prefetch i) + lgkm (reads of i-1)
    if (i + 1 < nIter) stage(smem + ((i + 1) & 1) * BUFSZ, (i + 1) * BK);

    const f16* As = (const f16*)(smem + (i & 1) * BUFSZ);
    const f16* Bs = As + 128 * BK;

    if constexpr (BK == 32) {
      f16x8 af[4], bf[4];
#pragma unroll
      for (int x = 0; x < 4; ++x)
        af[x] = *(const f16x8*)&As[(waveM + x * 16 + r16) * 32 + (quad ^ sw) * 8];
#pragma unroll
      for (int x = 0; x < 4; ++x)
        bf[x] = *(const f16x8*)&Bs[(waveN + x * 16 + r16) * 32 + (quad ^ sw) * 8];
#pragma unroll
      for (int x = 0; x < 4; ++x)
#pragma unroll
        for (int j = 0; j < 4; ++j)
          acc[x][j] =
              __builtin_amdgcn_mfma_f32_16x16x32_f16(af[x], bf[j], acc[x][j], 0, 0, 0);
    } else {
      f16x8 af[2][4], bf[2][4];
#pragma unroll
      for (int ks = 0; ks < 2; ++ks) {
#pragma unroll
        for (int x = 0; x < 4; ++x)
          af[ks][x] = *(const f16x8*)&As[(waveM + x * 16 + r16) * 64 +
                                         (((ks * 4 + quad) ^ (r16 & 7)) * 8)];
#pragma unroll
        for (int x = 0; x < 4; ++x)
          bf[ks][x] = *(const f16x8*)&Bs[(waveN + x * 16 + r16) * 64 +
                                         (((ks * 4 + quad) ^ (r16 & 7)) * 8)];
      }
#pragma unroll
      for (int ks = 0; ks < 2; ++ks)
#pragma unroll
        for (int x = 0; x < 4; ++x)
#pragma unroll
          for (int j = 0; j < 4; ++j)
            acc[x][j] = __builtin_amdgcn_mfma_f32_16x16x32_f16(af[ks][x], bf[ks][j],
                                                               acc[x][j], 0, 0, 0);
    }
  }

  // C/D layout (verified, dtype-independent): col = lane&15, row = quad*4 + reg.
  if constexpr (MODE == EPI_BIAS) {
#pragma unroll
    for (int j = 0; j < 4; ++j) {
      const int col = tileN + waveN + j * 16 + r16;
      const float bv = bias[col];
#pragma unroll
      for (int i = 0; i < 4; ++i) {
#pragma unroll
        for (int r = 0; r < 4; ++r) {
          const int row = tileM + waveM + i * 16 + quad * 4 + r;
          Cb[(size_t)row * ldc + col] = (OutT)(acc[i][j][r] * scale + bv);
        }
      }
    }
  } else if constexpr (MODE == EPI_QKV) {
    if (tileN < 2 * DD) {
      // packed QK output [8192 x 2048]
#pragma unroll
      for (int j = 0; j < 4; ++j) {
        const int col = tileN + waveN + j * 16 + r16;
        const float bv = bias[col];
#pragma unroll
        for (int i = 0; i < 4; ++i) {
#pragma unroll
          for (int r = 0; r < 4; ++r) {
            const int row = tileM + waveM + i * 16 + quad * 4 + r;
            Cb[(size_t)row * ldc + col] = (OutT)(acc[i][j][r] + bv);
          }
        }
      }
    } else {
      // V columns -> write transposed into Vt[b][d][s]
      const int b = tileM >> 11;  // 128-row tiles never straddle batch
      const int s0 = (tileM & 2047) + waveM;
      f16* vb = vt + (size_t)b * DD * SS;
#pragma unroll
      for (int j = 0; j < 4; ++j) {
        const int col = tileN + waveN + j * 16 + r16;
        const float bv = bias[col];
        const int d = col - 2 * DD;
#pragma unroll
        for (int i = 0; i < 4; ++i) {
          const int s = s0 + i * 16 + quad * 4;
          f16x4 v4;
#pragma unroll
          for (int r = 0; r < 4; ++r) v4[r] = (f16)(acc[i][j][r] + bv);
          *(f16x4*)&vb[(size_t)d * SS + s] = v4;
        }
      }
    }
  } else if constexpr (MODE == EPI_MASKEXP) {
    // Bitmask read: word(lr,lc) = lr*4 + (lc>>5), bit lc&31. Broadcast
    // across r16, 4 words across quads — conflict-free.
#pragma unroll
    for (int i = 0; i < 4; ++i) {
#pragma unroll
      for (int r = 0; r < 4; ++r) {
        const int lr = waveM + i * 16 + quad * 4 + r;
        const int row = tileM + lr;
        const uint32_t w0 = lmb[lr * 4 + (waveN >> 5)];
        const uint32_t w1 = lmb[lr * 4 + (waveN >> 5) + 1];
        float part = 0.0f;
#pragma unroll
        for (int j = 0; j < 4; ++j) {
          const int lc = waveN + j * 16 + r16;
          const int bitpos = j * 16 + r16;  // within w0:w1
          const uint32_t mv = ((j < 2 ? w0 : w1) >> (bitpos & 31)) & 1u;
          const float e = mv ? 0.0f : __expf(acc[i][j][r] * scale);
          Cb[(size_t)row * ldc + tileN + lc] = (OutT)e;
          part += e;
        }
#pragma unroll
        for (int d = 1; d < 16; d <<= 1) part += __shfl_xor(part, d, 64);
        if (r16 == 0) atomicAdd(&rowSum[bz * SS + row], part);
      }
    }
  } else {  // EPI_ROWSCALE
#pragma unroll
    for (int i = 0; i < 4; ++i) {
#pragma unroll
      for (int r = 0; r < 4; ++r) {
        const int row = tileM + waveM + i * 16 + quad * 4 + r;
        const float inv = scale / rowSum[bz * SS + row];
#pragma unroll
        for (int j = 0; j < 4; ++j) {
          const int col = tileN + waveN + j * 16 + r16;
          Cb[(size_t)row * ldc + col] = (OutT)(acc[i][j][r] * inv);
        }
      }
    }
  }
}

// ---------------------------------------------------------------------------
// Merged prep: X->f16 conv | W_qkv^T | W_out^T | rowSum zero, one dispatch.
// Block-uniform path select. grid = 8192 + 3072 + 1024 + 32 = 12320 x 256.
// ---------------------------------------------------------------------------
__global__ __launch_bounds__(256) void k_prep(
    const float* __restrict__ X, f16* __restrict__ Xh,
    const float* __restrict__ Wqkv, f16* __restrict__ Wqkvt,
    const float* __restrict__ Wout, f16* __restrict__ Woutt,
    float* __restrict__ rowSum) {
  int bid = blockIdx.x;
  const int t = threadIdx.x;
  if (bid < 8192) {  // X conv: 2097152 float4s
    const int i = bid * 256 + t;
    const float4 v = ((const float4*)X)[i];
    f16x4 h = {(f16)v.x, (f16)v.y, (f16)v.z, (f16)v.w};
    ((f16x4*)Xh)[i] = h;
    return;
  }
  bid -= 8192;
  __shared__ float tile[32][33];
  const int tx = t & 31, ty = t >> 5;
  if (bid < 3072) {  // Wqkv [1024][3072] -> Wqkvt [3072][1024]
    const int bx = (bid % 96) * 32, by = (bid / 96) * 32;
    for (int i2 = ty; i2 < 32; i2 += 8)
      tile[i2][tx] = Wqkv[(size_t)(by + i2) * 3072 + bx + tx];
    __syncthreads();
    for (int i2 = ty; i2 < 32; i2 += 8)
      Wqkvt[(size_t)(bx + i2) * 1024 + by + tx] = (f16)tile[tx][i2];
    return;
  }
  bid -= 3072;
  if (bid < 1024) {  // Wout [1024][1024] -> Woutt [1024][1024]
    const int bx = (bid & 31) * 32, by = (bid >> 5) * 32;
    for (int i2 = ty; i2 < 32; i2 += 8)
      tile[i2][tx] = Wout[(size_t)(by + i2) * 1024 + bx + tx];
    __syncthreads();
    for (int i2 = ty; i2 < 32; i2 += 8)
      Woutt[(size_t)(bx + i2) * 1024 + by + tx] = (f16)tile[tx][i2];
    return;
  }
  bid -= 1024;  // rowSum zero: 32 blocks x 256 = 8192
  rowSum[bid * 256 + t] = 0.0f;
}

// ---------------------------------------------------------------------------
// kernel_launch
// inputs: X[4,2048,1024]f32, mask[4,2048,2048]i32, W_qkv[1024,3072]f32,
//         b_qkv[3072]f32, W_out[1024,1024]f32, b_out[1024]f32
// out:    [4,2048,1024] f32
// ---------------------------------------------------------------------------
extern "C" void kernel_launch(void* const* d_in, const int* in_sizes, int n_in,
                              void* d_out, int out_size, void* d_ws, size_t ws_size,
                              hipStream_t stream) {
  const float* X = (const float*)d_in[0];
  const int* mask = (const int*)d_in[1];
  const float* Wqkv = (const float*)d_in[2];
  const float* bqkv = (const float*)d_in[3];
  const float* Wout = (const float*)d_in[4];
  const float* bout = (const float*)d_in[5];
  float* out = (float*)d_out;

  char* ws = (char*)d_ws;
  // ws layout (bytes); total ~125.9 MB
  f16* Xh = (f16*)(ws + 0);                    // 8192*1024   (16.78 MB)
  f16* Wqkvt = (f16*)(ws + 16777216);          // 3072*1024   ( 6.29 MB)
  f16* Woutt = (f16*)(ws + 23068672);          // 1024*1024   ( 2.10 MB)
  f16* QK = (f16*)(ws + 25165824);             // 8192*2048   (33.55 MB) packed Q|K
  f16* Vt = (f16*)(ws + 58720256);             // 4*1024*2048 (16.78 MB)
  f16* E = (f16*)(ws + 75497472);              // 4*2048*2048 (33.55 MB) exp(scores)
  f16* Ctx = (f16*)(ws + 109051904);           // 8192*1024   (16.78 MB)
  float* rowSum = (float*)(ws + 125829120);    // 8192 f32    (32 KB)

  // 1) merged prep: conv + both W transposes + rowSum zero
  k_prep<<<dim3(12320), dim3(256), 0, stream>>>(X, Xh, Wqkv, Wqkvt, Wout, Woutt,
                                                rowSum);

  // 2) QKV proj [8192 x 3072], K=1024: Q,K -> packed QK; V -> Vt (transposed)
  gemm_nt<f16, EPI_QKV, 32><<<dim3(24, 64, 1), dim3(256), 0, stream>>>(
      Xh, 0LL, DD, Wqkvt, 0LL, DD, QK, 0LL, 2 * DD, bqkv, nullptr, nullptr, Vt,
      1.0f, DD);

  // 3) E = where(mask, 0, exp(Q @ K^T / 32)); rowSum += row sums  [2048 x 2048] x4
  gemm_nt<f16, EPI_MASKEXP, 32><<<dim3(16, 16, 4), dim3(256), 0, stream>>>(
      QK, (long long)SS * 2 * DD, 2 * DD, QK + DD, (long long)SS * 2 * DD, 2 * DD,
      E, (long long)SS * SS, SS, nullptr, mask, rowSum, nullptr, 0.03125f, DD);

  // 4) ctx = (E @ V) / rowSum   [2048 x 1024] x4, K=2048. BK=64: grid-limited
  //    2 blocks/CU makes 64KB LDS occupancy-free; barriers 64 -> 32
  gemm_nt<f16, EPI_ROWSCALE, 64><<<dim3(8, 16, 4), dim3(256), 0, stream>>>(
      E, (long long)SS * SS, SS, Vt, (long long)DD * SS, SS, Ctx,
      (long long)SS * DD, DD, nullptr, nullptr, rowSum, nullptr, 1.0f, SS);

  // 5) out = ctx @ W_out + b   [8192 x 1024], K=1024, fp32 out. BK=64 likewise
  gemm_nt<float, EPI_BIAS, 64><<<dim3(8, 64, 1), dim3(256), 0, stream>>>(
      Ctx, 0LL, DD, Woutt, 0LL, DD, out, 0LL, DD, bout, nullptr, nullptr, nullptr,
      1.0f, DD);
}